// Round 13
// baseline (87.446 us; speedup 1.0000x reference)
//
#include <hip/hip_runtime.h>
#include <cstdint>

#define WPR 64                 // 64-bit words per row
#define NROWS 4096
#define NWORDS (WPR * NROWS)   // 2 MB board

#define KF 4                   // generations per dispatch (x8 dispatches)
#define OUTW 2                 // output rows per wave  (A/B change: was 4)
#define SPAN (OUTW + 2 * KF)   // 10 rows held in registers per wave
#define THREADS 256            // 4 waves/block
#define NBLK (NROWS / OUTW / 4)  // 512 blocks -> 2048 waves = 2 waves/SIMD
#define PACK_BLOCKS 2048

// ---------- pack float 0/1 grid -> bitboard + sum(x) partials; reset ticket -
__global__ __launch_bounds__(256) void pack_kernel(const float* __restrict__ x,
                                                   uint64_t* __restrict__ bits,
                                                   unsigned long long* __restrict__ px,
                                                   unsigned int* __restrict__ done) {
    int lane = threadIdx.x & 63;
    int wv = threadIdx.x >> 6;                 // 0..3
    int gw = blockIdx.x * 4 + wv;              // global wave 0..8191
    unsigned long long pc = 0;
    #pragma unroll
    for (int it = 0; it < 8; ++it) {
        int c = gw * 8 + it;                   // 256-cell chunk
        size_t base = (size_t)c * 256 + lane;
        uint64_t my = 0;
        #pragma unroll
        for (int j = 0; j < 4; ++j) {
            float v = x[base + (size_t)j * 64];    // coalesced 256B/wave
            uint64_t m = __ballot(v > 0.5f);
            if (lane == j) my = m;
        }
        if (lane < 4) {
            bits[(c << 2) + lane] = my;
            pc += (unsigned long long)__popcll(my);
        }
    }
    for (int off = 32; off; off >>= 1) pc += __shfl_down(pc, off, 64);
    __shared__ unsigned long long part[4];
    if (lane == 0) part[wv] = pc;
    __syncthreads();
    if (threadIdx.x == 0)
        px[blockIdx.x] = part[0] + part[1] + part[2] + part[3];
    if (blockIdx.x == 0 && threadIdx.x == 0)
        *done = 0u;                            // reset ticket every launch
}

// ---------- KF gens, fully wave-independent: NO barriers, NO LDS -----------
template <bool POP>
__global__ __launch_bounds__(THREADS) void step_kernel(
        const uint64_t* __restrict__ in, uint64_t* __restrict__ out,
        const unsigned long long* __restrict__ px,
        unsigned long long* __restrict__ py,
        unsigned int* __restrict__ done, float* __restrict__ res) {
    const int lane = threadIdx.x & 63;
    const int wv = threadIdx.x >> 6;            // 0..3
    const int w = blockIdx.x * 4 + wv;          // global wave 0..2047
    const int gbase = w * OUTW - KF;            // global row of span row 0

    // whole span in registers (out-of-board rows are 0 and STAY 0:
    // survival-only rule -> m=0 gives 0, no birth; no edge special-casing)
    uint64_t r[SPAN];
    #pragma unroll
    for (int i = 0; i < SPAN; ++i) {
        int gr = gbase + i;
        r[i] = (gr >= 0 && gr < NROWS) ? in[(size_t)gr * WPR + lane] : 0ULL;
    }

    #pragma unroll
    for (int g = 1; g <= KF; ++g) {            // fully static: guards vanish
        uint64_t sv[SPAN], cv[SPAN];
        uint32_t msgL = 0, msgR = 0;
        #pragma unroll
        for (int i = 0; i < SPAN; ++i) {
            if (i >= g && i < SPAN - g) {
                // vertical column sum r[i-1]+r[i]+r[i+1] = sv + 2*cv
                uint64_t a = r[i - 1], m = r[i], d = r[i + 1];
                uint64_t t = a ^ m;
                sv[i] = t ^ d;
                cv[i] = (a & m) | (d & t);
                // boundary bits for E/W word exchange (2 bits/row/direction)
                msgL |= ((uint32_t)(sv[i] >> 63) & 1u) << (2 * i);
                msgL |= ((uint32_t)(cv[i] >> 63) & 1u) << (2 * i + 1);
                msgR |= ((uint32_t)sv[i] & 1u) << (2 * i);
                msgR |= ((uint32_t)cv[i] & 1u) << (2 * i + 1);
            }
        }
        // the only cross-lane ops per generation: one shfl pair
        uint32_t fromL = __shfl_up(msgL, 1);
        uint32_t fromR = __shfl_down(msgR, 1);
        fromL = (lane == 0) ? 0u : fromL;      // board west edge
        fromR = (lane == 63) ? 0u : fromR;     // board east edge

        #pragma unroll
        for (int i = 0; i < SPAN; ++i) {
            if (i >= g && i < SPAN - g) {
                uint64_t sL = (sv[i] << 1) | (uint64_t)((fromL >> (2 * i)) & 1u);
                uint64_t cL = (cv[i] << 1) | (uint64_t)((fromL >> (2 * i + 1)) & 1u);
                uint64_t sR = (sv[i] >> 1) | ((uint64_t)((fromR >> (2 * i)) & 1u) << 63);
                uint64_t cR = (cv[i] >> 1) | ((uint64_t)((fromR >> (2 * i + 1)) & 1u) << 63);
                // N9 = (sL+sv+sR) + 2*(cL+cv+cR) = t0 + 2*(t1+u0) + 4*u1
                uint64_t t0, t1, u0, u1;
                { uint64_t tt = sL ^ sv[i]; t0 = tt ^ sR; t1 = (sL & sv[i]) | (sR & tt); }
                { uint64_t tt = cL ^ cv[i]; u0 = tt ^ cR; u1 = (cL & cv[i]) | (cR & tt); }
                uint64_t pp = t1 ^ u0, q = t1 & u0;
                uint64_t pred = (q & u1) | ((q ^ u1) & (pp | t0)); // N9>=5 <=> N8>=4
                r[i] &= pred;
            }
        }
    }

    if (!POP) {
        // publish the OUTW valid rows (span rows [KF, KF+OUTW))
        #pragma unroll
        for (int j = 0; j < OUTW; ++j)
            out[(size_t)(w * OUTW + j) * WPR + lane] = r[KF + j];
    } else {
        // final dispatch: sum(y) partial straight from registers + finalize
        unsigned long long pc = 0;
        #pragma unroll
        for (int j = 0; j < OUTW; ++j)
            pc += (unsigned long long)__popcll(r[KF + j]);
        for (int off = 32; off; off >>= 1) pc += __shfl_down(pc, off, 64);
        __shared__ unsigned long long part[4];
        __shared__ unsigned int ticket_s;
        __shared__ long long fin[4];
        if (lane == 0) part[wv] = pc;
        __syncthreads();
        if (threadIdx.x == 0) {
            py[blockIdx.x] = part[0] + part[1] + part[2] + part[3];
            __threadfence();                 // release partial before ticket
            ticket_s = atomicAdd(done, 1u);
        }
        __syncthreads();
        if (ticket_s == NBLK - 1) {          // last-arriving block finalizes
            __threadfence();                 // acquire all partials
            int t = threadIdx.x;
            long long v = 0;
            #pragma unroll
            for (int i = 0; i < PACK_BLOCKS / 256; ++i)
                v += (long long)px[t + i * 256];
            v -= (long long)py[t];
            v -= (long long)py[t + 256];
            for (int off = 32; off; off >>= 1) v += __shfl_down(v, off, 64);
            if (lane == 0) fin[wv] = v;
            __syncthreads();
            if (t == 0)
                res[0] = (float)(fin[0] + fin[1] + fin[2] + fin[3]); // exact f32
        }
    }
}

extern "C" void kernel_launch(void* const* d_in, const int* in_sizes, int n_in,
                              void* d_out, int out_size, void* d_ws, size_t ws_size,
                              hipStream_t stream) {
    const float* x = (const float*)d_in[0];
    float* out = (float*)d_out;

    uint8_t* ws = (uint8_t*)d_ws;
    uint64_t* buf0 = (uint64_t*)ws;                               // 2 MB
    uint64_t* buf1 = (uint64_t*)(ws + (size_t)NWORDS * 8);        // 2 MB
    unsigned long long* px = (unsigned long long*)(ws + (size_t)2 * NWORDS * 8); // 2048
    unsigned long long* py = px + PACK_BLOCKS;                                   // 512
    unsigned int* done = (unsigned int*)(py + NBLK);

    // 9 dispatches; no barriers/LDS in the step kernels at all
    pack_kernel<<<PACK_BLOCKS, 256, 0, stream>>>(x, buf0, px, done);
    step_kernel<false><<<NBLK, THREADS, 0, stream>>>(buf0, buf1, nullptr, nullptr, nullptr, nullptr);
    step_kernel<false><<<NBLK, THREADS, 0, stream>>>(buf1, buf0, nullptr, nullptr, nullptr, nullptr);
    step_kernel<false><<<NBLK, THREADS, 0, stream>>>(buf0, buf1, nullptr, nullptr, nullptr, nullptr);
    step_kernel<false><<<NBLK, THREADS, 0, stream>>>(buf1, buf0, nullptr, nullptr, nullptr, nullptr);
    step_kernel<false><<<NBLK, THREADS, 0, stream>>>(buf0, buf1, nullptr, nullptr, nullptr, nullptr);
    step_kernel<false><<<NBLK, THREADS, 0, stream>>>(buf1, buf0, nullptr, nullptr, nullptr, nullptr);
    step_kernel<false><<<NBLK, THREADS, 0, stream>>>(buf0, buf1, nullptr, nullptr, nullptr, nullptr);
    step_kernel<true ><<<NBLK, THREADS, 0, stream>>>(buf1, nullptr, px, py, done, out);
}

// Round 14
// 65.886 us; speedup vs baseline: 1.3272x; 1.3272x over previous
//
#include <hip/hip_runtime.h>
#include <cstdint>

#define WPR 64                 // 64-bit words per row
#define NROWS 4096
#define NWORDS (WPR * NROWS)   // 2 MB board

#define KF 8                   // generations fused per dispatch (x4 dispatches)
#define OUT 16                 // output rows per block
#define SPAN (OUT + 2 * KF)    // 32 span rows per block
#define RPW (SPAN / 8)         // 4 rows per wave (8 waves/block), contiguous
#define NBLK (NROWS / OUT)     // 256 blocks; 512 thr -> 2 waves/SIMD
#define PACK_BLOCKS 2048

// ---------- pack float 0/1 grid -> bitboard + sum(x) partials; reset ticket -
__global__ __launch_bounds__(256) void pack_kernel(const float* __restrict__ x,
                                                   uint64_t* __restrict__ bits,
                                                   unsigned long long* __restrict__ px,
                                                   unsigned int* __restrict__ done) {
    int lane = threadIdx.x & 63;
    int wv = threadIdx.x >> 6;                 // 0..3
    int gw = blockIdx.x * 4 + wv;              // global wave 0..8191
    unsigned long long pc = 0;
    #pragma unroll
    for (int it = 0; it < 8; ++it) {
        int c = gw * 8 + it;                   // 256-cell chunk
        size_t base = (size_t)c * 256 + lane;
        uint64_t my = 0;
        #pragma unroll
        for (int j = 0; j < 4; ++j) {
            float v = x[base + (size_t)j * 64];    // coalesced 256B/wave
            uint64_t m = __ballot(v > 0.5f);
            if (lane == j) my = m;
        }
        if (lane < 4) {
            bits[(c << 2) + lane] = my;
            pc += (unsigned long long)__popcll(my);
        }
    }
    for (int off = 32; off; off >>= 1) pc += __shfl_down(pc, off, 64);
    __shared__ unsigned long long part[4];
    if (lane == 0) part[wv] = pc;
    __syncthreads();
    if (threadIdx.x == 0)
        px[blockIdx.x] = part[0] + part[1] + part[2] + part[3];
    if (blockIdx.x == 0 && threadIdx.x == 0)
        *done = 0u;                            // reset ticket every launch
}

// ---------- KF=8 gens; contiguous rows, batched msg, LDS vertical halo -----
template <bool POP>
__global__ __launch_bounds__(512) void step_kernel(const uint64_t* __restrict__ in,
                                                   uint64_t* __restrict__ out,
                                                   const unsigned long long* __restrict__ px,
                                                   unsigned long long* __restrict__ py,
                                                   unsigned int* __restrict__ done,
                                                   float* __restrict__ res) {
    const int lane = threadIdx.x & 63;
    const int wv = threadIdx.x >> 6;       // 0..7
    const int b = blockIdx.x;
    const int w4 = wv * RPW;               // first span row owned by this wave
    const int gbase = b * OUT - KF;        // global row of span row 0

    uint64_t r[RPW];
    #pragma unroll
    for (int i = 0; i < RPW; ++i) {
        int gr = gbase + w4 + i;
        r[i] = (gr >= 0 && gr < NROWS) ? in[(size_t)gr * WPR + lane] : 0ULL;
    }

    __shared__ uint64_t bnd[2][8][2][64];  // [parity][wave][top/bot][lane]

    #pragma unroll
    for (int g = 1; g <= KF; ++g) {
        const int p = g & 1;
        bnd[p][wv][0][lane] = r[0];
        bnd[p][wv][1][lane] = r[RPW - 1];
        __syncthreads();
        uint64_t up = (wv > 0) ? bnd[p][wv - 1][1][lane] : 0ULL;
        uint64_t dn = (wv < 7) ? bnd[p][wv + 1][0][lane] : 0ULL;

        // phase A: vertical column sums (s,c), pyramid-guarded (wave-uniform)
        uint64_t sv[RPW], cv[RPW];
        uint32_t msgL = 0, msgR = 0;
        #pragma unroll
        for (int i = 0; i < RPW; ++i) {
            int sr = w4 + i;
            if (sr >= g && sr < SPAN - g) {
                uint64_t a = (i == 0) ? up : r[i - 1];
                uint64_t d = (i == RPW - 1) ? dn : r[i + 1];
                uint64_t m = r[i];
                uint64_t t = a ^ m;
                sv[i] = t ^ d;
                cv[i] = (a & m) | (d & t);
                msgL |= ((uint32_t)(sv[i] >> 63) & 1u) << (2 * i);
                msgL |= ((uint32_t)(cv[i] >> 63) & 1u) << (2 * i + 1);
                msgR |= ((uint32_t)sv[i] & 1u) << (2 * i);
                msgR |= ((uint32_t)cv[i] & 1u) << (2 * i + 1);
            } else { sv[i] = 0; cv[i] = 0; }
        }

        // one shfl pair for ALL rows' boundary bits (2 bits per row per dir)
        uint32_t fromL = __shfl_up(msgL, 1);
        uint32_t fromR = __shfl_down(msgR, 1);
        fromL = (lane == 0) ? 0u : fromL;
        fromR = (lane == 63) ? 0u : fromR;

        // phase B: horizontal CSA + survival predicate per valid row
        #pragma unroll
        for (int i = 0; i < RPW; ++i) {
            int sr = w4 + i;
            if (sr >= g && sr < SPAN - g) {
                uint64_t sL = (sv[i] << 1) | (uint64_t)((fromL >> (2 * i)) & 1u);
                uint64_t cL = (cv[i] << 1) | (uint64_t)((fromL >> (2 * i + 1)) & 1u);
                uint64_t sR = (sv[i] >> 1) | ((uint64_t)((fromR >> (2 * i)) & 1u) << 63);
                uint64_t cR = (cv[i] >> 1) | ((uint64_t)((fromR >> (2 * i + 1)) & 1u) << 63);
                uint64_t t0, t1, u0, u1;
                { uint64_t tt = sL ^ sv[i]; t0 = tt ^ sR; t1 = (sL & sv[i]) | (sR & tt); }
                { uint64_t tt = cL ^ cv[i]; u0 = tt ^ cR; u1 = (cL & cv[i]) | (cR & tt); }
                uint64_t pp = t1 ^ u0, q = t1 & u0;
                uint64_t pred = (q & u1) | ((q ^ u1) & (pp | t0)); // N9>=5 <=> N8>=4
                r[i] &= pred;
            }
        }
    }

    if (!POP) {
        // publish the OUT valid rows (span rows [KF, KF+OUT) -> waves 2..5)
        #pragma unroll
        for (int i = 0; i < RPW; ++i) {
            int sr = w4 + i;
            if (sr >= KF && sr < SPAN - KF)
                out[(size_t)(b * OUT + sr - KF) * WPR + lane] = r[i];
        }
    } else {
        // final dispatch: sum(y) partial straight from registers + finalize
        unsigned long long pc = 0;
        #pragma unroll
        for (int i = 0; i < RPW; ++i) {
            int sr = w4 + i;
            if (sr >= KF && sr < SPAN - KF)
                pc += (unsigned long long)__popcll(r[i]);
        }
        for (int off = 32; off; off >>= 1) pc += __shfl_down(pc, off, 64);
        __shared__ unsigned long long part[8];
        __shared__ unsigned int ticket_s;
        __shared__ long long fin[8];
        if (lane == 0) part[wv] = pc;
        __syncthreads();
        if (threadIdx.x == 0) {
            unsigned long long s = 0;
            #pragma unroll
            for (int i = 0; i < 8; ++i) s += part[i];
            py[b] = s;
            __threadfence();                 // release partial before ticket
            ticket_s = atomicAdd(done, 1u);
        }
        __syncthreads();
        if (ticket_s == NBLK - 1) {          // last-arriving block finalizes
            __threadfence();                 // acquire all partials
            int t = threadIdx.x;
            long long v = (long long)px[t] + (long long)px[t + 512] +
                          (long long)px[t + 1024] + (long long)px[t + 1536];
            if (t < NBLK) v -= (long long)py[t];
            for (int off = 32; off; off >>= 1) v += __shfl_down(v, off, 64);
            if (lane == 0) fin[wv] = v;
            __syncthreads();
            if (t == 0) {
                long long s = 0;
                #pragma unroll
                for (int i = 0; i < 8; ++i) s += fin[i];
                res[0] = (float)s;           // exact in f32 (|s| <= 2^24)
            }
        }
    }
}

extern "C" void kernel_launch(void* const* d_in, const int* in_sizes, int n_in,
                              void* d_out, int out_size, void* d_ws, size_t ws_size,
                              hipStream_t stream) {
    const float* x = (const float*)d_in[0];
    float* out = (float*)d_out;

    uint8_t* ws = (uint8_t*)d_ws;
    uint64_t* buf0 = (uint64_t*)ws;                               // 2 MB
    uint64_t* buf1 = (uint64_t*)(ws + (size_t)NWORDS * 8);        // 2 MB
    unsigned long long* px = (unsigned long long*)(ws + (size_t)2 * NWORDS * 8); // 2048
    unsigned long long* py = px + PACK_BLOCKS;                                   // 256
    unsigned int* done = (unsigned int*)(py + NBLK);

    // 5 dispatches; no memset, no grid.sync
    pack_kernel<<<PACK_BLOCKS, 256, 0, stream>>>(x, buf0, px, done);
    step_kernel<false><<<NBLK, 512, 0, stream>>>(buf0, buf1, nullptr, nullptr, nullptr, nullptr);
    step_kernel<false><<<NBLK, 512, 0, stream>>>(buf1, buf0, nullptr, nullptr, nullptr, nullptr);
    step_kernel<false><<<NBLK, 512, 0, stream>>>(buf0, buf1, nullptr, nullptr, nullptr, nullptr);
    step_kernel<true ><<<NBLK, 512, 0, stream>>>(buf1, nullptr, px, py, done, out);
}

// Round 15
// 60.709 us; speedup vs baseline: 1.4404x; 1.0853x over previous
//
#include <hip/hip_runtime.h>
#include <cstdint>

#define WPR 64                 // 64-bit words per row
#define NROWS 4096
#define NWORDS (WPR * NROWS)   // 2 MB board

#define KF 8                   // generations fused per dispatch (x4 dispatches)
#define OUT 16                 // output rows per block
#define SPAN (OUT + 2 * KF)    // 32 span rows per block
#define RPW (SPAN / 8)         // 4 rows per wave (8 waves/block), contiguous
#define NBLK (NROWS / OUT)     // 256 blocks; 512 thr -> 2 waves/SIMD
#define PACK_BLOCKS 2048

// ---------- pack float 0/1 grid -> bitboard + sum(x) partials; reset ticket -
__global__ __launch_bounds__(256) void pack_kernel(const float* __restrict__ x,
                                                   uint64_t* __restrict__ bits,
                                                   unsigned long long* __restrict__ px,
                                                   unsigned int* __restrict__ done) {
    int lane = threadIdx.x & 63;
    int wv = threadIdx.x >> 6;                 // 0..3
    int gw = blockIdx.x * 4 + wv;              // global wave 0..8191
    unsigned long long pc = 0;
    #pragma unroll
    for (int it = 0; it < 8; ++it) {
        int c = gw * 8 + it;                   // 256-cell chunk
        size_t base = (size_t)c * 256 + lane;
        uint64_t my = 0;
        #pragma unroll
        for (int j = 0; j < 4; ++j) {
            float v = x[base + (size_t)j * 64];    // coalesced 256B/wave
            uint64_t m = __ballot(v > 0.5f);
            if (lane == j) my = m;
        }
        if (lane < 4) {
            bits[(c << 2) + lane] = my;
            pc += (unsigned long long)__popcll(my);
        }
    }
    for (int off = 32; off; off >>= 1) pc += __shfl_down(pc, off, 64);
    __shared__ unsigned long long part[4];
    if (lane == 0) part[wv] = pc;
    __syncthreads();
    if (threadIdx.x == 0)
        px[blockIdx.x] = part[0] + part[1] + part[2] + part[3];
    if (blockIdx.x == 0 && threadIdx.x == 0)
        *done = 0u;                            // reset ticket every launch
}

// ---------- KF=8 gens; horizontal-first h-sums, LDS h-halo, batched shfl ---
template <bool POP>
__global__ __launch_bounds__(512) void step_kernel(const uint64_t* __restrict__ in,
                                                   uint64_t* __restrict__ out,
                                                   const unsigned long long* __restrict__ px,
                                                   unsigned long long* __restrict__ py,
                                                   unsigned int* __restrict__ done,
                                                   float* __restrict__ res) {
    const int lane = threadIdx.x & 63;
    const int wv = threadIdx.x >> 6;       // 0..7
    const int b = blockIdx.x;
    const int w4 = wv * RPW;               // first span row owned by this wave
    const int gbase = b * OUT - KF;        // global row of span row 0

    uint64_t r[RPW];
    #pragma unroll
    for (int i = 0; i < RPW; ++i) {
        int gr = gbase + w4 + i;
        r[i] = (gr >= 0 && gr < NROWS) ? in[(size_t)gr * WPR + lane] : 0ULL;
    }

    // [parity][wave][top/bot][hs/hc][lane] = 32 KB
    __shared__ uint64_t bnd[2][8][2][2][64];

    #pragma unroll
    for (int g = 1; g <= KF; ++g) {
        const int p = g & 1;

        // boundary-bit msgs straight from r (1 bit/row/dir) -> shfl at top,
        // latency hidden under the h-sum VALU work below
        uint32_t msgL = 0, msgR = 0;
        #pragma unroll
        for (int i = 0; i < RPW; ++i) {
            msgL |= ((uint32_t)(r[i] >> 63) & 1u) << i;
            msgR |= ((uint32_t)r[i] & 1u) << i;
        }
        uint32_t fromL = __shfl_up(msgL, 1);
        uint32_t fromR = __shfl_down(msgR, 1);
        fromL = (lane == 0) ? 0u : fromL;      // board west edge
        fromR = (lane == 63) ? 0u : fromR;     // board east edge

        // horizontal 3-sums h = hs + 2*hc for rows in h-range [g-1, SPAN-g]
        uint64_t hs[RPW], hc[RPW];
        #pragma unroll
        for (int i = 0; i < RPW; ++i) {
            int sr = w4 + i;
            if (sr >= g - 1 && sr <= SPAN - g) {
                uint64_t v = r[i];
                uint64_t hW = (v << 1) | (uint64_t)((fromL >> i) & 1u);
                uint64_t hE = (v >> 1) | ((uint64_t)((fromR >> i) & 1u) << 63);
                uint64_t t = hW ^ v;
                hs[i] = t ^ hE;
                hc[i] = (hW & v) | (hE & t);
            } else { hs[i] = 0; hc[i] = 0; }
        }

        // publish boundary-row h pairs for vertical neighbors
        bnd[p][wv][0][0][lane] = hs[0];
        bnd[p][wv][0][1][lane] = hc[0];
        bnd[p][wv][1][0][lane] = hs[RPW - 1];
        bnd[p][wv][1][1][lane] = hc[RPW - 1];
        __syncthreads();
        uint64_t uhs = (wv > 0) ? bnd[p][wv - 1][1][0][lane] : 0ULL;
        uint64_t uhc = (wv > 0) ? bnd[p][wv - 1][1][1][lane] : 0ULL;
        uint64_t dhs = (wv < 7) ? bnd[p][wv + 1][0][0][lane] : 0ULL;
        uint64_t dhc = (wv < 7) ? bnd[p][wv + 1][0][1][lane] : 0ULL;

        // vertical FA of three h's + survival predicate, rows [g, SPAN-g)
        #pragma unroll
        for (int i = 0; i < RPW; ++i) {
            int sr = w4 + i;
            if (sr >= g && sr < SPAN - g) {
                uint64_t as  = (i == 0) ? uhs : hs[i - 1];
                uint64_t ac  = (i == 0) ? uhc : hc[i - 1];
                uint64_t ds_ = (i == RPW - 1) ? dhs : hs[i + 1];
                uint64_t dc  = (i == RPW - 1) ? dhc : hc[i + 1];
                // ones = os + 2*oc ; twos = ws + 2*wc
                uint64_t t1 = as ^ hs[i];
                uint64_t os = t1 ^ ds_;
                uint64_t oc = (as & hs[i]) | (ds_ & t1);
                uint64_t t2 = ac ^ hc[i];
                uint64_t ws = t2 ^ dc;
                uint64_t wc = (ac & hc[i]) | (dc & t2);
                // N9 = os + 2*(oc+ws) + 4*wc ; survive <=> N9 >= 5
                uint64_t ps = oc ^ ws, pc = oc & ws;
                uint64_t pred = (pc & wc) | ((pc ^ wc) & (ps | os));
                r[i] &= pred;
            }
        }
    }

    if (!POP) {
        // publish the OUT valid rows (span rows [KF, KF+OUT))
        #pragma unroll
        for (int i = 0; i < RPW; ++i) {
            int sr = w4 + i;
            if (sr >= KF && sr < SPAN - KF)
                out[(size_t)(b * OUT + sr - KF) * WPR + lane] = r[i];
        }
    } else {
        // final dispatch: sum(y) partial straight from registers + finalize
        unsigned long long pc = 0;
        #pragma unroll
        for (int i = 0; i < RPW; ++i) {
            int sr = w4 + i;
            if (sr >= KF && sr < SPAN - KF)
                pc += (unsigned long long)__popcll(r[i]);
        }
        for (int off = 32; off; off >>= 1) pc += __shfl_down(pc, off, 64);
        __shared__ unsigned long long part[8];
        __shared__ unsigned int ticket_s;
        __shared__ long long fin[8];
        if (lane == 0) part[wv] = pc;
        __syncthreads();
        if (threadIdx.x == 0) {
            unsigned long long s = 0;
            #pragma unroll
            for (int i = 0; i < 8; ++i) s += part[i];
            py[b] = s;
            __threadfence();                 // release partial before ticket
            ticket_s = atomicAdd(done, 1u);
        }
        __syncthreads();
        if (ticket_s == NBLK - 1) {          // last-arriving block finalizes
            __threadfence();                 // acquire all partials
            int t = threadIdx.x;
            long long v = (long long)px[t] + (long long)px[t + 512] +
                          (long long)px[t + 1024] + (long long)px[t + 1536];
            if (t < NBLK) v -= (long long)py[t];
            for (int off = 32; off; off >>= 1) v += __shfl_down(v, off, 64);
            if (lane == 0) fin[wv] = v;
            __syncthreads();
            if (t == 0) {
                long long s = 0;
                #pragma unroll
                for (int i = 0; i < 8; ++i) s += fin[i];
                res[0] = (float)s;           // exact in f32 (|s| <= 2^24)
            }
        }
    }
}

extern "C" void kernel_launch(void* const* d_in, const int* in_sizes, int n_in,
                              void* d_out, int out_size, void* d_ws, size_t ws_size,
                              hipStream_t stream) {
    const float* x = (const float*)d_in[0];
    float* out = (float*)d_out;

    uint8_t* ws = (uint8_t*)d_ws;
    uint64_t* buf0 = (uint64_t*)ws;                               // 2 MB
    uint64_t* buf1 = (uint64_t*)(ws + (size_t)NWORDS * 8);        // 2 MB
    unsigned long long* px = (unsigned long long*)(ws + (size_t)2 * NWORDS * 8); // 2048
    unsigned long long* py = px + PACK_BLOCKS;                                   // 256
    unsigned int* done = (unsigned int*)(py + NBLK);

    // 5 dispatches; no memset, no grid.sync
    pack_kernel<<<PACK_BLOCKS, 256, 0, stream>>>(x, buf0, px, done);
    step_kernel<false><<<NBLK, 512, 0, stream>>>(buf0, buf1, nullptr, nullptr, nullptr, nullptr);
    step_kernel<false><<<NBLK, 512, 0, stream>>>(buf1, buf0, nullptr, nullptr, nullptr, nullptr);
    step_kernel<false><<<NBLK, 512, 0, stream>>>(buf0, buf1, nullptr, nullptr, nullptr, nullptr);
    step_kernel<true ><<<NBLK, 512, 0, stream>>>(buf1, nullptr, px, py, done, out);
}

// Round 16
// 59.788 us; speedup vs baseline: 1.4626x; 1.0154x over previous
//
#include <hip/hip_runtime.h>
#include <cstdint>

#define WPR 64                 // 64-bit words per row
#define NROWS 4096
#define NWORDS (WPR * NROWS)   // 2 MB board

#define KF 8                   // generations fused per dispatch (x4 dispatches)
#define OUT 16                 // output rows per block
#define SPAN (OUT + 2 * KF)    // 32 span rows per block
#define NWAVES 16              // 1024 threads -> 4 waves/SIMD (was 8 -> 2)
#define RPW (SPAN / NWAVES)    // 2 rows per wave, contiguous
#define NBLK (NROWS / OUT)     // 256 blocks = 1/CU
#define PACK_BLOCKS 2048

// ---------- pack float 0/1 grid -> bitboard + sum(x) partials; reset ticket -
__global__ __launch_bounds__(256) void pack_kernel(const float* __restrict__ x,
                                                   uint64_t* __restrict__ bits,
                                                   unsigned long long* __restrict__ px,
                                                   unsigned int* __restrict__ done) {
    int lane = threadIdx.x & 63;
    int wv = threadIdx.x >> 6;                 // 0..3
    int gw = blockIdx.x * 4 + wv;              // global wave 0..8191
    unsigned long long pc = 0;
    #pragma unroll
    for (int it = 0; it < 8; ++it) {
        int c = gw * 8 + it;                   // 256-cell chunk
        size_t base = (size_t)c * 256 + lane;
        uint64_t my = 0;
        #pragma unroll
        for (int j = 0; j < 4; ++j) {
            float v = x[base + (size_t)j * 64];    // coalesced 256B/wave
            uint64_t m = __ballot(v > 0.5f);
            if (lane == j) my = m;
        }
        if (lane < 4) {
            bits[(c << 2) + lane] = my;
            pc += (unsigned long long)__popcll(my);
        }
    }
    for (int off = 32; off; off >>= 1) pc += __shfl_down(pc, off, 64);
    __shared__ unsigned long long part[4];
    if (lane == 0) part[wv] = pc;
    __syncthreads();
    if (threadIdx.x == 0)
        px[blockIdx.x] = part[0] + part[1] + part[2] + part[3];
    if (blockIdx.x == 0 && threadIdx.x == 0)
        *done = 0u;                            // reset ticket every launch
}

// ---------- KF=8 gens; h-sums, LDS h-halo, 16 waves (4/SIMD) ---------------
template <bool POP>
__global__ __launch_bounds__(1024) void step_kernel(const uint64_t* __restrict__ in,
                                                    uint64_t* __restrict__ out,
                                                    const unsigned long long* __restrict__ px,
                                                    unsigned long long* __restrict__ py,
                                                    unsigned int* __restrict__ done,
                                                    float* __restrict__ res) {
    const int lane = threadIdx.x & 63;
    const int wv = threadIdx.x >> 6;       // 0..15
    const int b = blockIdx.x;
    const int w4 = wv * RPW;               // first span row owned by this wave
    const int gbase = b * OUT - KF;        // global row of span row 0

    uint64_t r[RPW];
    #pragma unroll
    for (int i = 0; i < RPW; ++i) {
        int gr = gbase + w4 + i;
        r[i] = (gr >= 0 && gr < NROWS) ? in[(size_t)gr * WPR + lane] : 0ULL;
    }

    // [parity][wave][top/bot][hs/hc][lane] = 64 KB
    __shared__ uint64_t bnd[2][NWAVES][2][2][64];

    #pragma unroll
    for (int g = 1; g <= KF; ++g) {
        const int p = g & 1;

        // boundary-bit msgs straight from r (1 bit/row/dir) -> shfl at top,
        // latency hidden under the h-sum VALU work below
        uint32_t msgL = 0, msgR = 0;
        #pragma unroll
        for (int i = 0; i < RPW; ++i) {
            msgL |= ((uint32_t)(r[i] >> 63) & 1u) << i;
            msgR |= ((uint32_t)r[i] & 1u) << i;
        }
        uint32_t fromL = __shfl_up(msgL, 1);
        uint32_t fromR = __shfl_down(msgR, 1);
        fromL = (lane == 0) ? 0u : fromL;      // board west edge
        fromR = (lane == 63) ? 0u : fromR;     // board east edge

        // horizontal 3-sums h = hs + 2*hc for rows in h-range [g-1, SPAN-g]
        uint64_t hs[RPW], hc[RPW];
        #pragma unroll
        for (int i = 0; i < RPW; ++i) {
            int sr = w4 + i;
            if (sr >= g - 1 && sr <= SPAN - g) {
                uint64_t v = r[i];
                uint64_t hW = (v << 1) | (uint64_t)((fromL >> i) & 1u);
                uint64_t hE = (v >> 1) | ((uint64_t)((fromR >> i) & 1u) << 63);
                uint64_t t = hW ^ v;
                hs[i] = t ^ hE;
                hc[i] = (hW & v) | (hE & t);
            } else { hs[i] = 0; hc[i] = 0; }
        }

        // publish boundary-row h pairs for vertical neighbors
        bnd[p][wv][0][0][lane] = hs[0];
        bnd[p][wv][0][1][lane] = hc[0];
        bnd[p][wv][1][0][lane] = hs[RPW - 1];
        bnd[p][wv][1][1][lane] = hc[RPW - 1];
        __syncthreads();
        uint64_t uhs = (wv > 0) ? bnd[p][wv - 1][1][0][lane] : 0ULL;
        uint64_t uhc = (wv > 0) ? bnd[p][wv - 1][1][1][lane] : 0ULL;
        uint64_t dhs = (wv < NWAVES - 1) ? bnd[p][wv + 1][0][0][lane] : 0ULL;
        uint64_t dhc = (wv < NWAVES - 1) ? bnd[p][wv + 1][0][1][lane] : 0ULL;

        // vertical FA of three h's + survival predicate, rows [g, SPAN-g)
        #pragma unroll
        for (int i = 0; i < RPW; ++i) {
            int sr = w4 + i;
            if (sr >= g && sr < SPAN - g) {
                uint64_t as  = (i == 0) ? uhs : hs[i - 1];
                uint64_t ac  = (i == 0) ? uhc : hc[i - 1];
                uint64_t ds_ = (i == RPW - 1) ? dhs : hs[i + 1];
                uint64_t dc  = (i == RPW - 1) ? dhc : hc[i + 1];
                // ones = os + 2*oc ; twos = ws + 2*wc
                uint64_t t1 = as ^ hs[i];
                uint64_t os = t1 ^ ds_;
                uint64_t oc = (as & hs[i]) | (ds_ & t1);
                uint64_t t2 = ac ^ hc[i];
                uint64_t ws = t2 ^ dc;
                uint64_t wc = (ac & hc[i]) | (dc & t2);
                // N9 = os + 2*(oc+ws) + 4*wc ; survive <=> N9 >= 5
                uint64_t ps = oc ^ ws, pc = oc & ws;
                uint64_t pred = (pc & wc) | ((pc ^ wc) & (ps | os));
                r[i] &= pred;
            }
        }
    }

    if (!POP) {
        // publish the OUT valid rows (span rows [KF, KF+OUT))
        #pragma unroll
        for (int i = 0; i < RPW; ++i) {
            int sr = w4 + i;
            if (sr >= KF && sr < SPAN - KF)
                out[(size_t)(b * OUT + sr - KF) * WPR + lane] = r[i];
        }
    } else {
        // final dispatch: sum(y) partial straight from registers + finalize
        unsigned long long pc = 0;
        #pragma unroll
        for (int i = 0; i < RPW; ++i) {
            int sr = w4 + i;
            if (sr >= KF && sr < SPAN - KF)
                pc += (unsigned long long)__popcll(r[i]);
        }
        for (int off = 32; off; off >>= 1) pc += __shfl_down(pc, off, 64);
        __shared__ unsigned long long part[NWAVES];
        __shared__ unsigned int ticket_s;
        __shared__ long long fin[NWAVES];
        if (lane == 0) part[wv] = pc;
        __syncthreads();
        if (threadIdx.x == 0) {
            unsigned long long s = 0;
            #pragma unroll
            for (int i = 0; i < NWAVES; ++i) s += part[i];
            py[b] = s;
            __threadfence();                 // release partial before ticket
            ticket_s = atomicAdd(done, 1u);
        }
        __syncthreads();
        if (ticket_s == NBLK - 1) {          // last-arriving block finalizes
            __threadfence();                 // acquire all partials
            int t = threadIdx.x;
            long long v = (long long)px[t] + (long long)px[t + 1024];
            if (t < NBLK) v -= (long long)py[t];
            for (int off = 32; off; off >>= 1) v += __shfl_down(v, off, 64);
            if (lane == 0) fin[wv] = v;
            __syncthreads();
            if (t == 0) {
                long long s = 0;
                #pragma unroll
                for (int i = 0; i < NWAVES; ++i) s += fin[i];
                res[0] = (float)s;           // exact in f32 (|s| <= 2^24)
            }
        }
    }
}

extern "C" void kernel_launch(void* const* d_in, const int* in_sizes, int n_in,
                              void* d_out, int out_size, void* d_ws, size_t ws_size,
                              hipStream_t stream) {
    const float* x = (const float*)d_in[0];
    float* out = (float*)d_out;

    uint8_t* ws = (uint8_t*)d_ws;
    uint64_t* buf0 = (uint64_t*)ws;                               // 2 MB
    uint64_t* buf1 = (uint64_t*)(ws + (size_t)NWORDS * 8);        // 2 MB
    unsigned long long* px = (unsigned long long*)(ws + (size_t)2 * NWORDS * 8); // 2048
    unsigned long long* py = px + PACK_BLOCKS;                                   // 256
    unsigned int* done = (unsigned int*)(py + NBLK);

    // 5 dispatches; no memset, no grid.sync
    pack_kernel<<<PACK_BLOCKS, 256, 0, stream>>>(x, buf0, px, done);
    step_kernel<false><<<NBLK, 1024, 0, stream>>>(buf0, buf1, nullptr, nullptr, nullptr, nullptr);
    step_kernel<false><<<NBLK, 1024, 0, stream>>>(buf1, buf0, nullptr, nullptr, nullptr, nullptr);
    step_kernel<false><<<NBLK, 1024, 0, stream>>>(buf0, buf1, nullptr, nullptr, nullptr, nullptr);
    step_kernel<true ><<<NBLK, 1024, 0, stream>>>(buf1, nullptr, px, py, done, out);
}